// Round 13
// baseline (2793.554 us; speedup 1.0000x reference)
//
#include <hip/hip_runtime.h>
#include <hip/hip_fp16.h>
#include <hip/hip_bf16.h>

typedef __attribute__((ext_vector_type(8))) short bf16x8;
typedef __attribute__((ext_vector_type(4))) float f32x4;

#define L2E  1.4426950408889634f
#define L2E2 2.8853901817779268f

__device__ __forceinline__ short f2bf(float f) {
    unsigned u = __builtin_bit_cast(unsigned, f);
    unsigned r = (u + 0x7FFFu + ((u >> 16) & 1u)) >> 16;
    return (short)r;
}
__device__ __forceinline__ float fast_rcp(float x) {
    return __builtin_amdgcn_rcpf(x);
}
// weights/inputs prescaled by log2e (z,r) / 2*log2e (h) -> raw exp2
__device__ __forceinline__ float exp2n(float x) {
    return __builtin_amdgcn_exp2f(-x);
}

// ---------------------------------------------------------------------------
// Prep: transpose + convert weights to bf16, PRESCALED: z/r cols x log2e,
// h cols x 2*log2e (folds exp/tanh input scaling into the weights).
// ---------------------------------------------------------------------------
__global__ __launch_bounds__(256) void prep_kernel(
    const float* __restrict__ kf, const float* __restrict__ kb,
    const float* __restrict__ rf, const float* __restrict__ rb,
    short* __restrict__ kT, short* __restrict__ rTf, short* __restrict__ rTb)
{
    int idx = blockIdx.x * 256 + threadIdx.x;   // 0 .. 1536*256-1
    int n = idx >> 8;
    int k = idx & 255;
    const float* src = (n < 768) ? kf : kb;
    int nn = (n < 768) ? n : (n - 768);
    float sc = (nn < 512) ? L2E : L2E2;
    kT[idx] = f2bf(src[k * 768 + nn] * sc);
    if (n < 768) {
        float sc2 = (n < 512) ? L2E : L2E2;
        rTf[idx] = f2bf(rf[k * 768 + n] * sc2);
        rTb[idx] = f2bf(rb[k * 768 + n] * sc2);
    }
}

// ---------------------------------------------------------------------------
// Projection GEMM: xw = (x@kernel + bias0 (+bias1 z,r)) * gate_scale.
// Output layout PERMUTED for the gru kernel's per-lane register loads
// (R8-proven):
//   per (dir): region16 (64MB): [bg(4)][t(1024)][wt(16)][lane(64)][8 halves]
//              region8  (32MB, at +64MB): [bg][t][wt][lane][4 halves]
// ---------------------------------------------------------------------------
__global__ __launch_bounds__(256) void proj_kernel(
    const float* __restrict__ x, const short* __restrict__ kT,
    const float* __restrict__ bias_f, const float* __restrict__ bias_b,
    char* __restrict__ xwp_f, char* __restrict__ xwp_b)
{
    __shared__ short lA[64][264];
    __shared__ short lB[128][264];

    const int tid = threadIdx.x;
    const int m0 = blockIdx.x * 64;        // 64 consecutive m = same batch row
    const int n0 = blockIdx.y * 128;

    const int b_blk  = m0 >> 10;
    const int bg     = b_blk >> 4;
    const int rowg   = b_blk & 15;
    const int hi_t   = rowg >> 2;
    const int i_t    = rowg & 3;
    const int tbase  = m0 & 1023;

#pragma unroll
    for (int rep = 0; rep < 16; ++rep) {
        int lin = rep * 256 + tid;
        int r = lin >> 6;
        int c4 = lin & 63;
        float4 v = *(const float4*)(x + (size_t)(m0 + r) * 256 + c4 * 4);
        short4 s;
        s.x = f2bf(v.x); s.y = f2bf(v.y); s.z = f2bf(v.z); s.w = f2bf(v.w);
        *(short4*)&lA[r][c4 * 4] = s;
    }
#pragma unroll
    for (int rep = 0; rep < 16; ++rep) {
        int lin = rep * 256 + tid;
        int r = lin >> 5;
        int c8 = lin & 31;
        uint4 v = *(const uint4*)(kT + (size_t)(n0 + r) * 256 + c8 * 8);
        *(uint4*)&lB[r][c8 * 8] = v;
    }
    __syncthreads();

    const int w = tid >> 6, l = tid & 63;
    const int l15 = l & 15, hi = l >> 4;

    bf16x8 a[8];
#pragma unroll
    for (int kt = 0; kt < 8; ++kt)
        a[kt] = *(const bf16x8*)&lA[w * 16 + l15][kt * 32 + hi * 8];

#pragma unroll
    for (int j = 0; j < 8; ++j) {
        f32x4 acc = {0.f, 0.f, 0.f, 0.f};
#pragma unroll
        for (int kt = 0; kt < 8; ++kt) {
            bf16x8 b = *(const bf16x8*)&lB[j * 16 + l15][kt * 32 + hi * 8];
            acc = __builtin_amdgcn_mfma_f32_16x16x32_bf16(a[kt], b, acc, 0, 0, 0);
        }
        int ng = n0 + j * 16 + l15;
        int dirb = ng >= 768;
        int nn = ng - (dirb ? 768 : 0);
        const float* bias = dirb ? bias_b : bias_f;
        float sc = (nn < 512) ? L2E : L2E2;
        float badd = (bias[nn] + ((nn < 512) ? bias[768 + nn] : 0.f)) * sc;
        char* basep = dirb ? xwp_b : xwp_f;

        int g   = nn >> 8;           // 0=z, 1=r, 2=h
        int cg2 = nn & 255;
        int wt  = cg2 >> 4;
        int lane_t = hi_t * 16 + (cg2 & 15);

#pragma unroll
        for (int i = 0; i < 4; ++i) {
            int t = tbase + w * 16 + hi * 4 + i;
            unsigned short hv = __builtin_bit_cast(unsigned short,
                                    __float2half(acc[i] + badd));
            if (g < 2) {
                *(unsigned short*)(basep + ((size_t)bg << 24) + ((size_t)t << 14)
                                   + (wt << 10) + (lane_t << 4) + ((g * 4 + i_t) << 1)) = hv;
            } else {
                *(unsigned short*)(basep + 67108864u + ((size_t)bg << 23) + ((size_t)t << 13)
                                   + (wt << 9) + (lane_t << 3) + (i_t << 1)) = hv;
            }
        }
    }
}

// ---------------------------------------------------------------------------
// Recurrence: 8 blocks (2 dirs x 4 groups of 16 batch rows), 1024 threads.
// Wave w owns h-columns [16w,16w+16).  (R8 structure, proven.)
//  - 21 of 24 rec B-fragments register-resident; 3 (Bh[5..7]) in LDS
//    per-lane frag layout (48 b128 reads/step, conflict-free).
//  - h state in MFMA A-FRAGMENT layout, double-buffered (stride-1 b128).
//  - xw per-lane dwordx4+dwordx2 issued at step start, consumed post-MFMA.
//  - weights prescaled -> raw exp2 gates; b1h folded into ah acc init.
//  - h->bf16 via v_cvt_pk_bf16_f32; ONE lgkm-only raw barrier per step.
// ---------------------------------------------------------------------------
#define GRU_STEP(PR, PW)                                                     \
  {                                                                          \
    uint4  xv16 = *(const uint4*)xp16;  xp16 += step16;                      \
    uint2  xv8  = *(const uint2*)xp8;   xp8  += step8;                       \
    unsigned bbase = 0;                                                      \
    asm volatile("" : "+v"(bbase));   /* defeat cross-step LDS-read hoist */ \
    f32x4 az = {0.f,0.f,0.f,0.f}, ar = {0.f,0.f,0.f,0.f};                    \
    f32x4 ah = {b1h, b1h, b1h, b1h};                                         \
    _Pragma("unroll") for (int kt = 0; kt < 8; ++kt) {                       \
      bf16x8 aq = *(const bf16x8*)((const char*)hfrag + (PR)*8192            \
                                   + kt * 1024 + l * 16);                    \
      bf16x8 bh;                                                             \
      if (kt < 5) bh = Bh[kt];                                               \
      else bh = *(const bf16x8*)((const char*)bfrag + bbase                  \
                                 + (kt - 5) * 16384 + w * 1024 + l * 16);    \
      az = __builtin_amdgcn_mfma_f32_16x16x32_bf16(aq, Bz[kt], az, 0,0,0);   \
      ar = __builtin_amdgcn_mfma_f32_16x16x32_bf16(aq, Br[kt], ar, 0,0,0);   \
      ah = __builtin_amdgcn_mfma_f32_16x16x32_bf16(aq, bh, ah, 0,0,0);       \
    }                                                                        \
    const __half* hx  = (const __half*)&xv16;                                \
    const __half* hx8 = (const __half*)&xv8;                                 \
    float hn[4];                                                             \
    _Pragma("unroll") for (int i = 0; i < 4; ++i) {                          \
      float zi  = fast_rcp(1.f + exp2n(__half2float(hx[i]) + az[i]));        \
      float rri = fast_rcp(1.f + exp2n(__half2float(hx[4+i]) + ar[i]));      \
      float pre = __fmaf_rn(rri, ah[i], __half2float(hx8[i]));               \
      float q   = fast_rcp(1.f + exp2n(pre));                                \
      float hh  = 2.f * q - 1.f;                                             \
      float h2  = hh + zi * (hold[i] - hh);                                  \
      hold[i] = h2;  hn[i] = h2;                                             \
      opbase[i * 524288] = h2;                                               \
    }                                                                        \
    unsigned pk0, pk1;                                                       \
    asm("v_cvt_pk_bf16_f32 %0, %1, %2" : "=v"(pk0) : "v"(hn[0]), "v"(hn[1]));\
    asm("v_cvt_pk_bf16_f32 %0, %1, %2" : "=v"(pk1) : "v"(hn[2]), "v"(hn[3]));\
    {                                                                        \
      char* hb = (char*)hfrag + (PW)*8192 + wb;                              \
      *(short*)(hb)      = (short)(pk0 & 0xffff);                            \
      *(short*)(hb + 16) = (short)(pk0 >> 16);                               \
      *(short*)(hb + 32) = (short)(pk1 & 0xffff);                            \
      *(short*)(hb + 48) = (short)(pk1 >> 16);                               \
    }                                                                        \
    opbase += ostep;                                                         \
    asm volatile("s_waitcnt lgkmcnt(0)\n\ts_barrier" ::: "memory");          \
  }

__global__ __launch_bounds__(1024) void gru_kernel(
    const char* __restrict__ xwp_f, const char* __restrict__ xwp_b,
    const short* __restrict__ recT_f, const short* __restrict__ recT_b,
    const float* __restrict__ bias_f, const float* __restrict__ bias_b,
    float* __restrict__ out)
{
    __shared__ short hfrag[2][8][64][8];      // h in A-frag layout, 16KB
    __shared__ short bfrag[3][16][64][8];     // offloaded Bh[5..7], 48KB

    const int tid = threadIdx.x;
    const int w = tid >> 6, l = tid & 63;
    const int l15 = l & 15, hi = l >> 4;
    const int dir = blockIdx.x >> 2;
    const int bg  = blockIdx.x & 3;
    const int b0  = bg * 16;

    const char*  xwp  = dir ? xwp_b  : xwp_f;
    const short* recT = dir ? recT_b : recT_f;
    const float* bias = dir ? bias_b : bias_f;

    const int cg = w * 16 + l15;
    const float b1h = bias[768 + 512 + cg] * L2E2;   // prescaled rec bias (h)

    // zero both hfrag buffers (16KB = 1024 x int4)
    ((int4*)hfrag)[tid] = make_int4(0, 0, 0, 0);

    // rec-kernel B fragments: 21 to registers, 3 (Bh[5..7]) to LDS
    const char* recTc = (const char*)recT;
    unsigned offz = (((unsigned)(cg)       * 256u) + hi * 8u) * 2u;
    unsigned offr = (((unsigned)(256 + cg) * 256u) + hi * 8u) * 2u;
    unsigned offh = (((unsigned)(512 + cg) * 256u) + hi * 8u) * 2u;
    bf16x8 Bz[8], Br[8], Bh[5];
#pragma unroll
    for (int kt = 0; kt < 8; ++kt) {
        Bz[kt] = *(const bf16x8*)(recTc + offz + kt * 64);
        Br[kt] = *(const bf16x8*)(recTc + offr + kt * 64);
    }
#pragma unroll
    for (int kt = 0; kt < 5; ++kt)
        Bh[kt] = *(const bf16x8*)(recTc + offh + kt * 64);
#pragma unroll
    for (int kt = 5; kt < 8; ++kt) {
        bf16x8 tmp = *(const bf16x8*)(recTc + offh + kt * 64);
        *(bf16x8*)((char*)bfrag + (kt - 5) * 16384 + w * 1024 + l * 16) = tmp;
    }

    // xw per-lane streaming pointers (permuted layout)
    const int t0 = dir ? 1023 : 0;
    const long step16 = dir ? -16384 : 16384;
    const long step8  = dir ? -8192  : 8192;
    const char* xp16 = xwp + ((size_t)bg << 24) + ((size_t)t0 << 14)
                       + (w << 10) + (l << 4);
    const char* xp8  = xwp + 67108864u + ((size_t)bg << 23) + ((size_t)t0 << 13)
                       + (w << 9) + (l << 3);

    // out: rows b0+hi*4+i, column dir*256+cg, time t
    const long ostep = dir ? -512 : 512;
    float* opbase = out + (size_t)(b0 + hi * 4) * 524288 + (size_t)t0 * 512
                    + (size_t)dir * 256 + cg;

    // h-write byte offset within an hfrag buffer (A-frag position of (row, cg))
    const unsigned wb = (unsigned)(cg >> 5) * 1024u
                      + ((((unsigned)cg >> 3) & 3u) * 16u) * 16u
                      + (unsigned)(hi * 4) * 16u + ((unsigned)(l15 & 7)) * 2u;

    f32x4 hold = {0.f, 0.f, 0.f, 0.f};
    __syncthreads();      // hfrag zeros + bfrag writes visible

    for (int su = 0; su < 512; ++su) {
        GRU_STEP(0, 1)
        GRU_STEP(1, 0)
    }
}

// ---------------------------------------------------------------------------
extern "C" void kernel_launch(void* const* d_in, const int* in_sizes, int n_in,
                              void* d_out, int out_size, void* d_ws, size_t ws_size,
                              hipStream_t stream) {
    const float* x   = (const float*)d_in[0];
    const float* kf  = (const float*)d_in[1];
    const float* rf  = (const float*)d_in[2];
    const float* bf_ = (const float*)d_in[3];
    const float* kb  = (const float*)d_in[4];
    const float* rb  = (const float*)d_in[5];
    const float* bb_ = (const float*)d_in[6];

    char* ws = (char*)d_ws;
    char* xwp_f = ws;                                 // 96MB permuted xw (fwd)
    char* xwp_b = ws + 100663296;                     // 96MB permuted xw (bwd)
    short* rTf  = (short*)(ws + 201326592);           // 768*256 bf16
    short* rTb  = (short*)(ws + 201719808);
    short* kT   = (short*)(ws + 202113024);           // 1536*256 bf16
    float* out  = (float*)d_out;

    hipLaunchKernelGGL(prep_kernel, dim3(1536), dim3(256), 0, stream,
                       kf, kb, rf, rb, kT, rTf, rTb);
    hipLaunchKernelGGL(proj_kernel, dim3(1024, 12), dim3(256), 0, stream,
                       x, kT, bf_, bb_, xwp_f, xwp_b);
    hipLaunchKernelGGL(gru_kernel, dim3(8), dim3(1024), 0, stream,
                       xwp_f, xwp_b, rTf, rTb, bf_, bb_, out);
}

// Round 15
// 1776.106 us; speedup vs baseline: 1.5729x; 1.5729x over previous
//
#include <hip/hip_runtime.h>
#include <hip/hip_fp16.h>
#include <hip/hip_bf16.h>

typedef __attribute__((ext_vector_type(8))) short bf16x8;
typedef __attribute__((ext_vector_type(4))) float f32x4;
typedef __attribute__((ext_vector_type(2))) __fp16 f16x2;

__device__ __forceinline__ short f2bf(float f) {
    unsigned u = __builtin_bit_cast(unsigned, f);
    unsigned r = (u + 0x7FFFu + ((u >> 16) & 1u)) >> 16;
    return (short)r;
}
__device__ __forceinline__ float fast_rcp(float x) {
    return __builtin_amdgcn_rcpf(x);
}
__device__ __forceinline__ float fast_exp(float x) {
    return __builtin_amdgcn_exp2f(x * 1.4426950408889634f);
}

// ---------------------------------------------------------------------------
// Prep: transpose + convert weights to bf16.  (R8-identical)
// ---------------------------------------------------------------------------
__global__ __launch_bounds__(256) void prep_kernel(
    const float* __restrict__ kf, const float* __restrict__ kb,
    const float* __restrict__ rf, const float* __restrict__ rb,
    short* __restrict__ kT, short* __restrict__ rTf, short* __restrict__ rTb)
{
    int idx = blockIdx.x * 256 + threadIdx.x;   // 0 .. 1536*256-1
    int n = idx >> 8;
    int k = idx & 255;
    const float* src = (n < 768) ? kf : kb;
    int nn = (n < 768) ? n : (n - 768);
    kT[idx] = f2bf(src[k * 768 + nn]);
    if (n < 768) {
        rTf[idx] = f2bf(rf[k * 768 + n]);
        rTb[idx] = f2bf(rb[k * 768 + n]);
    }
}

// ---------------------------------------------------------------------------
// Projection GEMM: xw = x@kernel + bias0 (+bias1 folded for z,r).
// Output layout identical to R8 (permuted for gru per-lane loads):
//   region16 (64MB/dir): [bg(4)][t(1024)][wt(16)][lane_t(64)][8 halves]
//   region8  (32MB/dir, at +64MB): [bg][t][wt][lane_t][4 halves]
//   lane_t = hi_t*16 + (col&15), slots i_t = b&3, hi_t = (b&15)>>2.
// M-TILING: block = {4 batch rows (bg,hi_t) x 16 t} x 128 cols, so each
// block owns whole 16B/8B chunks -> packed dwordx2 stores (v_cvt_pkrtz),
// 8 stores/thread instead of 32 scalar u16.
// Row mapping: rr = w*16 + hi*4 + i  ->  t = tbase16 + w*4 + hi, b_loc = i.
// ---------------------------------------------------------------------------
__global__ __launch_bounds__(256) void proj_kernel(
    const float* __restrict__ x, const short* __restrict__ kT,
    const float* __restrict__ bias_f, const float* __restrict__ bias_b,
    char* __restrict__ xwp_f, char* __restrict__ xwp_b)
{
    __shared__ short lA[64][264];
    __shared__ short lB[128][264];

    const int tid = threadIdx.x;
    const int bt   = blockIdx.x;           // 0..1023
    const int tbase16 = (bt >> 4) * 16;    // 16-t tile
    const int bg   = (bt & 15) >> 2;
    const int hi_t = bt & 3;
    const int n0 = blockIdx.y * 128;

    // stage A: 64 rows = (b_loc = r&3, t_loc = r>>2), coalesced per row
#pragma unroll
    for (int rep = 0; rep < 16; ++rep) {
        int lin = rep * 256 + tid;
        int r = lin >> 6;
        int c4 = lin & 63;
        int bb = bg * 16 + hi_t * 4 + (r & 3);
        int tt = tbase16 + (r >> 2);
        float4 v = *(const float4*)(x + ((size_t)bb * 1024 + tt) * 256 + c4 * 4);
        short4 s;
        s.x = f2bf(v.x); s.y = f2bf(v.y); s.z = f2bf(v.z); s.w = f2bf(v.w);
        *(short4*)&lA[r][c4 * 4] = s;
    }
#pragma unroll
    for (int rep = 0; rep < 16; ++rep) {
        int lin = rep * 256 + tid;
        int r = lin >> 5;
        int c8 = lin & 31;
        uint4 v = *(const uint4*)(kT + (size_t)(n0 + r) * 256 + c8 * 8);
        *(uint4*)&lB[r][c8 * 8] = v;
    }
    __syncthreads();

    const int w = tid >> 6, l = tid & 63;
    const int l15 = l & 15, hi = l >> 4;

    bf16x8 a[8];
#pragma unroll
    for (int kt = 0; kt < 8; ++kt)
        a[kt] = *(const bf16x8*)&lA[w * 16 + l15][kt * 32 + hi * 8];

    const int t_row   = tbase16 + w * 4 + hi;     // this lane's t (all i share)
    const int lane_t  = hi_t * 16 + l15;

#pragma unroll
    for (int j = 0; j < 8; ++j) {
        f32x4 acc = {0.f, 0.f, 0.f, 0.f};
#pragma unroll
        for (int kt = 0; kt < 8; ++kt) {
            bf16x8 b = *(const bf16x8*)&lB[j * 16 + l15][kt * 32 + hi * 8];
            acc = __builtin_amdgcn_mfma_f32_16x16x32_bf16(a[kt], b, acc, 0, 0, 0);
        }
        int ng   = n0 + j * 16;            // uniform per j (l15 only in low 4)
        int dirb = ng >= 768;
        int nn0  = ng - (dirb ? 768 : 0);
        int g    = nn0 >> 8;               // 0=z, 1=r, 2=h
        int wtj  = (nn0 & 255) >> 4;
        const float* bias = dirb ? bias_b : bias_f;
        char* basep = dirb ? xwp_b : xwp_f;
        int nn = nn0 + l15;
        float badd = bias[nn] + ((nn < 512) ? bias[768 + nn] : 0.f);

        f16x2 lo2 = __builtin_amdgcn_cvt_pkrtz(acc[0] + badd, acc[1] + badd);
        f16x2 hi2 = __builtin_amdgcn_cvt_pkrtz(acc[2] + badd, acc[3] + badd);
        uint2 pk;
        pk.x = __builtin_bit_cast(unsigned, lo2);
        pk.y = __builtin_bit_cast(unsigned, hi2);

        if (g < 2) {
            *(uint2*)(basep + ((size_t)bg << 24) + ((size_t)t_row << 14)
                      + (wtj << 10) + (lane_t << 4) + (g * 8)) = pk;
        } else {
            *(uint2*)(basep + 67108864u + ((size_t)bg << 23)
                      + ((size_t)t_row << 13) + (wtj << 9) + (lane_t << 3)) = pk;
        }
    }
}

// ---------------------------------------------------------------------------
// Recurrence: 8 blocks (2 dirs x 4 groups of 16 batch rows), 1024 threads.
// BYTE-IDENTICAL to R8 (proven 1525 us, absmax 0.0117).
// ---------------------------------------------------------------------------
#define GRU_STEP(PR, PW)                                                     \
  {                                                                          \
    uint4  xv16 = *(const uint4*)xp16;  xp16 += step16;                      \
    uint2  xv8  = *(const uint2*)xp8;   xp8  += step8;                       \
    unsigned bbase = 0;                                                      \
    asm volatile("" : "+v"(bbase));   /* defeat cross-step LDS-read hoist */ \
    f32x4 az = {0.f,0.f,0.f,0.f}, ar = {0.f,0.f,0.f,0.f},                    \
          ah = {0.f,0.f,0.f,0.f};                                           \
    _Pragma("unroll") for (int kt = 0; kt < 8; ++kt) {                       \
      bf16x8 aq = *(const bf16x8*)((const char*)hfrag + (PR)*8192            \
                                   + kt * 1024 + l * 16);                    \
      bf16x8 bh;                                                             \
      if (kt < 5) bh = Bh[kt];                                               \
      else bh = *(const bf16x8*)((const char*)bfrag + bbase                  \
                                 + (kt - 5) * 16384 + w * 1024 + l * 16);    \
      az = __builtin_amdgcn_mfma_f32_16x16x32_bf16(aq, Bz[kt], az, 0,0,0);   \
      ar = __builtin_amdgcn_mfma_f32_16x16x32_bf16(aq, Br[kt], ar, 0,0,0);   \
      ah = __builtin_amdgcn_mfma_f32_16x16x32_bf16(aq, bh, ah, 0,0,0);       \
    }                                                                        \
    const __half* hx  = (const __half*)&xv16;                                \
    const __half* hx8 = (const __half*)&xv8;                                 \
    float hn[4];                                                             \
    _Pragma("unroll") for (int i = 0; i < 4; ++i) {                          \
      float zi  = fast_rcp(1.f + fast_exp(-(__half2float(hx[i]) + az[i])));  \
      float rri = fast_rcp(1.f + fast_exp(-(__half2float(hx[4+i]) + ar[i])));\
      float pre = __half2float(hx8[i]) + rri * (ah[i] + b1h);                \
      float sg  = fast_rcp(1.f + fast_exp(-2.f * pre));                      \
      float hh  = 2.f * sg - 1.f;                                            \
      float h2  = hh + zi * (hold[i] - hh);                                  \
      hold[i] = h2;  hn[i] = h2;                                             \
      opbase[i * 524288] = h2;                                               \
    }                                                                        \
    unsigned pk0, pk1;                                                       \
    asm("v_cvt_pk_bf16_f32 %0, %1, %2" : "=v"(pk0) : "v"(hn[0]), "v"(hn[1]));\
    asm("v_cvt_pk_bf16_f32 %0, %1, %2" : "=v"(pk1) : "v"(hn[2]), "v"(hn[3]));\
    {                                                                        \
      char* hb = (char*)hfrag + (PW)*8192 + wb;                              \
      *(short*)(hb)      = (short)(pk0 & 0xffff);                            \
      *(short*)(hb + 16) = (short)(pk0 >> 16);                               \
      *(short*)(hb + 32) = (short)(pk1 & 0xffff);                            \
      *(short*)(hb + 48) = (short)(pk1 >> 16);                               \
    }                                                                        \
    opbase += ostep;                                                         \
    asm volatile("s_waitcnt lgkmcnt(0)\n\ts_barrier" ::: "memory");          \
  }

__global__ __launch_bounds__(1024) void gru_kernel(
    const char* __restrict__ xwp_f, const char* __restrict__ xwp_b,
    const short* __restrict__ recT_f, const short* __restrict__ recT_b,
    const float* __restrict__ bias_f, const float* __restrict__ bias_b,
    float* __restrict__ out)
{
    __shared__ short hfrag[2][8][64][8];      // h in A-frag layout, 16KB
    __shared__ short bfrag[3][16][64][8];     // offloaded Bh[5..7], 48KB

    const int tid = threadIdx.x;
    const int w = tid >> 6, l = tid & 63;
    const int l15 = l & 15, hi = l >> 4;
    const int dir = blockIdx.x >> 2;
    const int bg  = blockIdx.x & 3;
    const int b0  = bg * 16;

    const char*  xwp  = dir ? xwp_b  : xwp_f;
    const short* recT = dir ? recT_b : recT_f;
    const float* bias = dir ? bias_b : bias_f;

    const int cg = w * 16 + l15;
    const float b1h = bias[768 + 512 + cg];

    // zero both hfrag buffers (16KB = 1024 x int4)
    ((int4*)hfrag)[tid] = make_int4(0, 0, 0, 0);

    // rec-kernel B fragments: 21 to registers, 3 (Bh[5..7]) to LDS
    const char* recTc = (const char*)recT;
    unsigned offz = (((unsigned)(cg)       * 256u) + hi * 8u) * 2u;
    unsigned offr = (((unsigned)(256 + cg) * 256u) + hi * 8u) * 2u;
    unsigned offh = (((unsigned)(512 + cg) * 256u) + hi * 8u) * 2u;
    bf16x8 Bz[8], Br[8], Bh[5];
#pragma unroll
    for (int kt = 0; kt < 8; ++kt) {
        Bz[kt] = *(const bf16x8*)(recTc + offz + kt * 64);
        Br[kt] = *(const bf16x8*)(recTc + offr + kt * 64);
    }
#pragma unroll
    for (int kt = 0; kt < 5; ++kt)
        Bh[kt] = *(const bf16x8*)(recTc + offh + kt * 64);
#pragma unroll
    for (int kt = 5; kt < 8; ++kt) {
        bf16x8 tmp = *(const bf16x8*)(recTc + offh + kt * 64);
        *(bf16x8*)((char*)bfrag + (kt - 5) * 16384 + w * 1024 + l * 16) = tmp;
    }

    // xw per-lane streaming pointers (permuted layout)
    const int t0 = dir ? 1023 : 0;
    const long step16 = dir ? -16384 : 16384;
    const long step8  = dir ? -8192  : 8192;
    const char* xp16 = xwp + ((size_t)bg << 24) + ((size_t)t0 << 14)
                       + (w << 10) + (l << 4);
    const char* xp8  = xwp + 67108864u + ((size_t)bg << 23) + ((size_t)t0 << 13)
                       + (w << 9) + (l << 3);

    // out: rows b0+hi*4+i, column dir*256+cg, time t
    const long ostep = dir ? -512 : 512;
    float* opbase = out + (size_t)(b0 + hi * 4) * 524288 + (size_t)t0 * 512
                    + (size_t)dir * 256 + cg;

    // h-write byte offset within an hfrag buffer (A-frag position of (row, cg))
    const unsigned wb = (unsigned)(cg >> 5) * 1024u
                      + ((((unsigned)cg >> 3) & 3u) * 16u) * 16u
                      + (unsigned)(hi * 4) * 16u + ((unsigned)(l15 & 7)) * 2u;

    f32x4 hold = {0.f, 0.f, 0.f, 0.f};
    __syncthreads();      // hfrag zeros + bfrag writes visible

    for (int su = 0; su < 512; ++su) {
        GRU_STEP(0, 1)
        GRU_STEP(1, 0)
    }
}

// ---------------------------------------------------------------------------
extern "C" void kernel_launch(void* const* d_in, const int* in_sizes, int n_in,
                              void* d_out, int out_size, void* d_ws, size_t ws_size,
                              hipStream_t stream) {
    const float* x   = (const float*)d_in[0];
    const float* kf  = (const float*)d_in[1];
    const float* rf  = (const float*)d_in[2];
    const float* bf_ = (const float*)d_in[3];
    const float* kb  = (const float*)d_in[4];
    const float* rb  = (const float*)d_in[5];
    const float* bb_ = (const float*)d_in[6];

    char* ws = (char*)d_ws;
    char* xwp_f = ws;                                 // 96MB permuted xw (fwd)
    char* xwp_b = ws + 100663296;                     // 96MB permuted xw (bwd)
    short* rTf  = (short*)(ws + 201326592);           // 768*256 bf16
    short* rTb  = (short*)(ws + 201719808);
    short* kT   = (short*)(ws + 202113024);           // 1536*256 bf16
    float* out  = (float*)d_out;

    hipLaunchKernelGGL(prep_kernel, dim3(1536), dim3(256), 0, stream,
                       kf, kb, rf, rb, kT, rTf, rTb);
    hipLaunchKernelGGL(proj_kernel, dim3(1024, 12), dim3(256), 0, stream,
                       x, kT, bf_, bb_, xwp_f, xwp_b);
    hipLaunchKernelGGL(gru_kernel, dim3(8), dim3(1024), 0, stream,
                       xwp_f, xwp_b, rTf, rTb, bf_, bb_, out);
}